// Round 4
// baseline (440.449 us; speedup 1.0000x reference)
//
#include <hip/hip_runtime.h>
#include <hip/hip_bf16.h>

#define S_LEN 2048
#define D_MODEL 768
#define NH 12
#define DK 64
#define F_DIM 3072
#define BATCH 2
#define M_ROWS (BATCH * S_LEN)   // 4096

typedef __bf16 bf16x8 __attribute__((ext_vector_type(8)));
typedef float floatx4 __attribute__((ext_vector_type(4)));
typedef unsigned short u16;

__device__ inline float bf2f(u16 u) {
    union { unsigned int i; float f; } x; x.i = ((unsigned int)u) << 16; return x.f;
}
__device__ inline u16 f2bf(float f) {
    union { float f; unsigned int i; } x; x.f = f;
    unsigned int r = x.i + 0x7fffu + ((x.i >> 16) & 1u);
    return (u16)(r >> 16);
}

// async global->LDS, 16B per lane; LDS dest is wave-uniform base + lane*16
__device__ __forceinline__ void ldsload16(const u16* g, u16* l) {
    __builtin_amdgcn_global_load_lds(
        (const __attribute__((address_space(1))) unsigned int*)g,
        (__attribute__((address_space(3))) unsigned int*)l, 16, 0, 0);
}

// ---------------- f32 -> bf16 convert (weights) ----------------
__global__ __launch_bounds__(256)
void cvt_k(const float4* __restrict__ in, ushort4* __restrict__ out, int n4) {
    int i = blockIdx.x * 256 + threadIdx.x;
    if (i < n4) {
        float4 v = in[i];
        ushort4 o;
        o.x = f2bf(v.x); o.y = f2bf(v.y); o.z = f2bf(v.z); o.w = f2bf(v.w);
        out[i] = o;
    }
}

// ---------------- RMSNorm: f32 in, bf16 out, one block per row --------------
__global__ __launch_bounds__(256)
void rmsnorm_k(const float* __restrict__ x, const float* __restrict__ g, u16* __restrict__ out) {
    int row = blockIdx.x;
    const float* xr = x + (size_t)row * D_MODEL;
    u16* orow = out + (size_t)row * D_MODEL;
    int t = threadIdx.x;
    float v0 = xr[t];
    float v1 = xr[t + 256];
    float v2 = xr[t + 512];
    float ss = v0 * v0 + v1 * v1 + v2 * v2;
    #pragma unroll
    for (int off = 1; off < 64; off <<= 1) ss += __shfl_xor(ss, off);
    __shared__ float red[4];
    if ((t & 63) == 0) red[t >> 6] = ss;
    __syncthreads();
    float tot = red[0] + red[1] + red[2] + red[3];
    float scale = rsqrtf(tot * (1.0f / (float)D_MODEL) + 1e-5f);
    orow[t]       = f2bf(g[t]       * v0 * scale);
    orow[t + 256] = f2bf(g[t + 256] * v1 * scale);
    orow[t + 512] = f2bf(g[t + 512] * v2 * scale);
}

// ---------------- 128x128-tile GEMM (m97 structure) -------------------------
// acc[M,N] = A[M,K] @ W[N,K]^T, bf16 in, fp32 acc.
// MODE 1: C(f32) = acc + R(f32)
// MODE 2: C(bf16) = silu(acc1) * acc3  (dual weights B1=w1, B2=w3)
template <int MODE>
__global__ __launch_bounds__(256)
void gemm128(const u16* __restrict__ A, const u16* __restrict__ B1,
             const u16* __restrict__ B2, const float* __restrict__ R,
             void* __restrict__ Cout, int N, int K) {
    __shared__ u16 As[128][32];
    __shared__ u16 Bs[128][32];
    __shared__ u16 Bs2[(MODE == 2) ? 128 : 1][32];

    int t = threadIdx.x;
    int w = t >> 6, lane = t & 63;
    int mBase = blockIdx.y * 128, nBase = blockIdx.x * 128;
    int lrow = lane & 15, quad = lane >> 4;
    int wm = (w >> 1) * 64, wn = (w & 1) * 64;

    int srow = lane >> 2;
    int scol = (lane & 3) * 8;
    const u16* Ag  = A  + (size_t)(mBase + w * 32 + srow) * K + scol;
    const u16* Bg  = B1 + (size_t)(nBase + w * 32 + srow) * K + scol;
    const u16* B2g = (MODE == 2) ? (B2 + (size_t)(nBase + w * 32 + srow) * K + scol) : nullptr;
    u16* AsL0 = &As[w * 32][0];      u16* AsL1 = &As[w * 32 + 16][0];
    u16* BsL0 = &Bs[w * 32][0];      u16* BsL1 = &Bs[w * 32 + 16][0];
    u16* Bs2L0 = &Bs2[(MODE == 2) ? w * 32 : 0][0];
    u16* Bs2L1 = &Bs2[(MODE == 2) ? w * 32 + 16 : 0][0];

    floatx4 zero = {0.f, 0.f, 0.f, 0.f};
    floatx4 acc[4][4], acc2[(MODE == 2) ? 4 : 1][(MODE == 2) ? 4 : 1];
    #pragma unroll
    for (int r = 0; r < 4; ++r)
        #pragma unroll
        for (int c = 0; c < 4; ++c) acc[r][c] = zero;
    if (MODE == 2)
        #pragma unroll
        for (int r = 0; r < 4; ++r)
            #pragma unroll
            for (int c = 0; c < 4; ++c) acc2[r][c] = zero;

    for (int k0 = 0; k0 < K; k0 += 32) {
        __syncthreads();
        ldsload16(Ag + k0, AsL0);
        ldsload16(Ag + (size_t)16 * K + k0, AsL1);
        ldsload16(Bg + k0, BsL0);
        ldsload16(Bg + (size_t)16 * K + k0, BsL1);
        if (MODE == 2) {
            ldsload16(B2g + k0, Bs2L0);
            ldsload16(B2g + (size_t)16 * K + k0, Bs2L1);
        }
        __syncthreads();

        bf16x8 af[4];
        #pragma unroll
        for (int r = 0; r < 4; ++r) af[r] = *(const bf16x8*)&As[wm + r * 16 + lrow][quad * 8];
        #pragma unroll
        for (int c = 0; c < 4; ++c) {
            bf16x8 bfr = *(const bf16x8*)&Bs[wn + c * 16 + lrow][quad * 8];
            #pragma unroll
            for (int r = 0; r < 4; ++r)
                acc[r][c] = __builtin_amdgcn_mfma_f32_16x16x32_bf16(af[r], bfr, acc[r][c], 0, 0, 0);
            if (MODE == 2) {
                bf16x8 b2f = *(const bf16x8*)&Bs2[wn + c * 16 + lrow][quad * 8];
                #pragma unroll
                for (int r = 0; r < 4; ++r)
                    acc2[r][c] = __builtin_amdgcn_mfma_f32_16x16x32_bf16(af[r], b2f, acc2[r][c], 0, 0, 0);
            }
        }
    }

    #pragma unroll
    for (int r = 0; r < 4; ++r) {
        #pragma unroll
        for (int c = 0; c < 4; ++c) {
            #pragma unroll
            for (int j = 0; j < 4; ++j) {
                int grow = mBase + wm + r * 16 + quad * 4 + j;
                int gcol = nBase + wn + c * 16 + lrow;
                size_t idx = (size_t)grow * N + gcol;
                float val = acc[r][c][j];
                if (MODE == 1) {
                    ((float*)Cout)[idx] = val + R[idx];
                } else {
                    float a = val;
                    ((u16*)Cout)[idx] = f2bf((a / (1.0f + __expf(-a))) * acc2[r][c][j]);
                }
            }
        }
    }
}

// ---------------- fused QKV GEMM (N = 3*768), V stored transposed -----------
__global__ __launch_bounds__(256)
void gemm_qkv(const u16* __restrict__ A, const u16* __restrict__ wq,
              const u16* __restrict__ wk, const u16* __restrict__ wv,
              u16* __restrict__ qb, u16* __restrict__ kb, u16* __restrict__ vt) {
    const int K = D_MODEL;
    __shared__ u16 As[128][32];
    __shared__ u16 Bs[128][32];

    int t = threadIdx.x;
    int w = t >> 6, lane = t & 63;
    int nb = blockIdx.x;
    int which = nb / 6;
    int mBase = blockIdx.y * 128, nBase = (nb % 6) * 128;
    const u16* B1 = (which == 0) ? wq : (which == 1) ? wk : wv;
    int lrow = lane & 15, quad = lane >> 4;
    int wm = (w >> 1) * 64, wn = (w & 1) * 64;

    int srow = lane >> 2;
    int scol = (lane & 3) * 8;
    const u16* Ag = A  + (size_t)(mBase + w * 32 + srow) * K + scol;
    const u16* Bg = B1 + (size_t)(nBase + w * 32 + srow) * K + scol;
    u16* AsL0 = &As[w * 32][0];  u16* AsL1 = &As[w * 32 + 16][0];
    u16* BsL0 = &Bs[w * 32][0];  u16* BsL1 = &Bs[w * 32 + 16][0];

    floatx4 zero = {0.f, 0.f, 0.f, 0.f};
    floatx4 acc[4][4];
    #pragma unroll
    for (int r = 0; r < 4; ++r)
        #pragma unroll
        for (int c = 0; c < 4; ++c) acc[r][c] = zero;

    for (int k0 = 0; k0 < K; k0 += 32) {
        __syncthreads();
        ldsload16(Ag + k0, AsL0);
        ldsload16(Ag + (size_t)16 * K + k0, AsL1);
        ldsload16(Bg + k0, BsL0);
        ldsload16(Bg + (size_t)16 * K + k0, BsL1);
        __syncthreads();

        bf16x8 af[4];
        #pragma unroll
        for (int r = 0; r < 4; ++r) af[r] = *(const bf16x8*)&As[wm + r * 16 + lrow][quad * 8];
        #pragma unroll
        for (int c = 0; c < 4; ++c) {
            bf16x8 bfr = *(const bf16x8*)&Bs[wn + c * 16 + lrow][quad * 8];
            #pragma unroll
            for (int r = 0; r < 4; ++r)
                acc[r][c] = __builtin_amdgcn_mfma_f32_16x16x32_bf16(af[r], bfr, acc[r][c], 0, 0, 0);
        }
    }

    u16* dst = (which == 0) ? qb : kb;
    #pragma unroll
    for (int r = 0; r < 4; ++r) {
        #pragma unroll
        for (int c = 0; c < 4; ++c) {
            #pragma unroll
            for (int j = 0; j < 4; ++j) {
                int grow = mBase + wm + r * 16 + quad * 4 + j;
                int gcol = nBase + wn + c * 16 + lrow;
                float val = acc[r][c][j];
                if (which == 2) {
                    int bb = grow >> 11, s = grow & 2047;
                    int hh = gcol >> 6, d = gcol & 63;
                    vt[((((size_t)bb * NH + hh) * DK + d) << 11) + s] = f2bf(val);
                } else {
                    dst[(size_t)grow * D_MODEL + gcol] = f2bf(val);
                }
            }
        }
    }
}

// ---------------- MFMA flash attention -------------------------------------
// Block: 64 q-rows of one (b,h); 4 waves, wave w owns q-rows w*16..w*16+15.
// P = exp(S/8)*mask unnormalized (scores O(1), no max subtraction needed),
// row-sum deferred to epilogue. V pre-transposed [d][s].
__global__ __launch_bounds__(256)
void attn_mfma(const u16* __restrict__ q, const u16* __restrict__ k,
               const u16* __restrict__ vt, const int* __restrict__ mask,
               u16* __restrict__ out) {
    __shared__ u16 Qs0[64][32], Qs1[64][32];
    __shared__ u16 Ks0[64][32], Ks1[64][32];
    __shared__ u16 Vs0[64][32], Vs1[64][32];
    __shared__ u16 Ms[64][72];
    __shared__ u16 Ps[4][16][72];

    int t = threadIdx.x;
    int lane = t & 63;
    int w = t >> 6;
    int lrow = lane & 15;
    int quad = lane >> 4;

    int st0 = blockIdx.x * 64;
    int bh = blockIdx.y;
    int h = bh % NH;
    int b = bh / NH;

    const u16* qbase = q + ((size_t)b * S_LEN + st0) * D_MODEL + h * DK;
    const u16* kbase = k + (size_t)b * S_LEN * D_MODEL + h * DK;
    const u16* vbase = vt + (size_t)bh * DK * S_LEN;
    const int* mbase = mask + ((size_t)b * S_LEN + st0) * S_LEN;

    int srow = lane >> 2;          // staging row within 16-row chunk
    int scol = (lane & 3) * 8;     // staging col (elems)

    // ---- stage Q tile (64x64) once ----
    const u16* qg = qbase + (size_t)(w * 16 + srow) * D_MODEL + scol;
    ldsload16(qg, &Qs0[w * 16][0]);
    ldsload16(qg + 32, &Qs1[w * 16][0]);
    __syncthreads();
    bf16x8 aq0 = *(const bf16x8*)&Qs0[w * 16 + lrow][quad * 8];
    bf16x8 aq1 = *(const bf16x8*)&Qs1[w * 16 + lrow][quad * 8];

    const u16* kg = kbase + (size_t)(w * 16 + srow) * D_MODEL + scol;
    const u16* vg = vbase + (size_t)(w * 16 + srow) * S_LEN + scol;

    floatx4 zero = {0.f, 0.f, 0.f, 0.f};
    floatx4 Ot[4] = {zero, zero, zero, zero};
    float lsum[4] = {0.f, 0.f, 0.f, 0.f};

    for (int kt = 0; kt < S_LEN; kt += 64) {
        __syncthreads();   // previous tile's LDS reads done
        ldsload16(kg + (size_t)kt * D_MODEL, &Ks0[w * 16][0]);
        ldsload16(kg + (size_t)kt * D_MODEL + 32, &Ks1[w * 16][0]);
        ldsload16(vg + kt, &Vs0[w * 16][0]);
        ldsload16(vg + kt + 32, &Vs1[w * 16][0]);
        // mask tile 64x64 ints -> bf16 0/1 in LDS (coalesced int4 loads)
        #pragma unroll
        for (int it = 0; it < 4; ++it) {
            int i = t + it * 256;
            int row = i >> 4, c4 = (i & 15) * 4;
            int4 mv = *(const int4*)(mbase + (size_t)row * S_LEN + kt + c4);
            ushort4 o;
            o.x = mv.x ? 0x3F80 : 0; o.y = mv.y ? 0x3F80 : 0;
            o.z = mv.z ? 0x3F80 : 0; o.w = mv.w ? 0x3F80 : 0;
            *(ushort4*)&Ms[row][c4] = o;
        }
        __syncthreads();

        // --- S = Q K^T  (16 q-rows x 64 keys per wave) ---
        floatx4 st[4];
        #pragma unroll
        for (int nt = 0; nt < 4; ++nt) {
            bf16x8 bk0 = *(const bf16x8*)&Ks0[nt * 16 + lrow][quad * 8];
            bf16x8 bk1 = *(const bf16x8*)&Ks1[nt * 16 + lrow][quad * 8];
            st[nt] = __builtin_amdgcn_mfma_f32_16x16x32_bf16(aq0, bk0, zero, 0, 0, 0);
            st[nt] = __builtin_amdgcn_mfma_f32_16x16x32_bf16(aq1, bk1, st[nt], 0, 0, 0);
        }

        // --- P = mask * exp(S/8); stash to LDS in A-layout; row-sums ---
        #pragma unroll
        for (int j = 0; j < 4; ++j) {
            int qrow = w * 16 + quad * 4 + j;
            #pragma unroll
            for (int nt = 0; nt < 4; ++nt) {
                float m = bf2f(Ms[qrow][nt * 16 + lrow]);
                float e = m * __expf(st[nt][j] * 0.125f);
                lsum[j] += e;
                Ps[w][quad * 4 + j][nt * 16 + lrow] = f2bf(e);
            }
        }

        // --- O += P V ---
        bf16x8 ap0 = *(const bf16x8*)&Ps[w][lrow][quad * 8];
        bf16x8 ap1 = *(const bf16x8*)&Ps[w][lrow][32 + quad * 8];
        #pragma unroll
        for (int dt = 0; dt < 4; ++dt) {
            bf16x8 bv0 = *(const bf16x8*)&Vs0[dt * 16 + lrow][quad * 8];
            bf16x8 bv1 = *(const bf16x8*)&Vs1[dt * 16 + lrow][quad * 8];
            Ot[dt] = __builtin_amdgcn_mfma_f32_16x16x32_bf16(ap0, bv0, Ot[dt], 0, 0, 0);
            Ot[dt] = __builtin_amdgcn_mfma_f32_16x16x32_bf16(ap1, bv1, Ot[dt], 0, 0, 0);
        }
    }

    // --- row sums across the 16 lanes of each quad, then write O / l ---
    #pragma unroll
    for (int j = 0; j < 4; ++j) {
        #pragma unroll
        for (int off = 1; off < 16; off <<= 1) lsum[j] += __shfl_xor(lsum[j], off);
        lsum[j] = 1.0f / lsum[j];
    }
    u16* obase = out + ((size_t)b * S_LEN + st0 + w * 16) * D_MODEL + h * DK;
    #pragma unroll
    for (int dt = 0; dt < 4; ++dt)
        #pragma unroll
        for (int j = 0; j < 4; ++j)
            obase[(size_t)(quad * 4 + j) * D_MODEL + dt * 16 + lrow] = f2bf(Ot[dt][j] * lsum[j]);
}

// ---------------- host launch ----------------
extern "C" void kernel_launch(void* const* d_in, const int* in_sizes, int n_in,
                              void* d_out, int out_size, void* d_ws, size_t ws_size,
                              hipStream_t stream) {
    const float* x      = (const float*)d_in[0];
    const int*   mask   = (const int*)d_in[1];
    const float* wq     = (const float*)d_in[2];
    const float* wk     = (const float*)d_in[3];
    const float* wv     = (const float*)d_in[4];
    const float* wo     = (const float*)d_in[5];
    const float* w1     = (const float*)d_in[6];
    const float* w2     = (const float*)d_in[7];
    const float* w3     = (const float*)d_in[8];
    const float* g_attn = (const float*)d_in[9];
    const float* g_ffn  = (const float*)d_in[10];
    float* out = (float*)d_out;

    const size_t WSMALL = (size_t)D_MODEL * D_MODEL;
    const size_t WBIG   = (size_t)F_DIM * D_MODEL;
    const size_t MD     = (size_t)M_ROWS * D_MODEL;

    char* ws = (char*)d_ws;
    u16* wqb = (u16*)ws;             ws += WSMALL * 2;
    u16* wkb = (u16*)ws;             ws += WSMALL * 2;
    u16* wvb = (u16*)ws;             ws += WSMALL * 2;
    u16* wob = (u16*)ws;             ws += WSMALL * 2;
    u16* w1b = (u16*)ws;             ws += WBIG * 2;
    u16* w2b = (u16*)ws;             ws += WBIG * 2;
    u16* w3b = (u16*)ws;             ws += WBIG * 2;
    u16* xn  = (u16*)ws;             ws += MD * 2;       // also hn (reuse)
    u16* qb  = (u16*)ws;             ws += MD * 2;       // qb..ao contiguous = ub [M,F]
    u16* kb  = (u16*)ws;             ws += MD * 2;
    u16* vb  = (u16*)ws;             ws += MD * 2;       // V^T [B][NH][DK][S]
    u16* ao  = (u16*)ws;             ws += MD * 2;
    float* hb = (float*)ws;          ws += MD * 4;
    u16* hn = xn;
    u16* ub = qb;   // [M, F] bf16, reuses qb..ao (4*MD == M*F)
    (void)ws_size; (void)n_in; (void)in_sizes; (void)out_size;

    dim3 blk(256);

    cvt_k<<<(WSMALL / 4 + 255) / 256, blk, 0, stream>>>((const float4*)wq, (ushort4*)wqb, WSMALL / 4);
    cvt_k<<<(WSMALL / 4 + 255) / 256, blk, 0, stream>>>((const float4*)wk, (ushort4*)wkb, WSMALL / 4);
    cvt_k<<<(WSMALL / 4 + 255) / 256, blk, 0, stream>>>((const float4*)wv, (ushort4*)wvb, WSMALL / 4);
    cvt_k<<<(WSMALL / 4 + 255) / 256, blk, 0, stream>>>((const float4*)wo, (ushort4*)wob, WSMALL / 4);
    cvt_k<<<(WBIG / 4 + 255) / 256, blk, 0, stream>>>((const float4*)w1, (ushort4*)w1b, WBIG / 4);
    cvt_k<<<(WBIG / 4 + 255) / 256, blk, 0, stream>>>((const float4*)w2, (ushort4*)w2b, WBIG / 4);
    cvt_k<<<(WBIG / 4 + 255) / 256, blk, 0, stream>>>((const float4*)w3, (ushort4*)w3b, WBIG / 4);

    rmsnorm_k<<<M_ROWS, blk, 0, stream>>>(x, g_attn, xn);
    gemm_qkv<<<dim3(18, M_ROWS / 128), blk, 0, stream>>>(xn, wqb, wkb, wvb, qb, kb, vb);
    attn_mfma<<<dim3(S_LEN / 64, BATCH * NH), blk, 0, stream>>>(qb, kb, vb, mask, ao);
    gemm128<1><<<dim3(D_MODEL / 128, M_ROWS / 128), blk, 0, stream>>>(ao, wob, nullptr, x, hb, D_MODEL, D_MODEL);
    rmsnorm_k<<<M_ROWS, blk, 0, stream>>>((const float*)hb, g_ffn, hn);
    gemm128<2><<<dim3(F_DIM / 128, M_ROWS / 128), blk, 0, stream>>>(hn, w1b, w3b, nullptr, ub, F_DIM, D_MODEL);
    gemm128<1><<<dim3(D_MODEL / 128, M_ROWS / 128), blk, 0, stream>>>(ub, w2b, nullptr, hb, out, D_MODEL, F_DIM);
}

// Round 5
// 399.446 us; speedup vs baseline: 1.1027x; 1.1027x over previous
//
#include <hip/hip_runtime.h>
#include <hip/hip_bf16.h>

#define S_LEN 2048
#define D_MODEL 768
#define NH 12
#define DK 64
#define F_DIM 3072
#define BATCH 2
#define M_ROWS (BATCH * S_LEN)   // 4096

typedef __bf16 bf16x8 __attribute__((ext_vector_type(8)));
typedef float floatx4 __attribute__((ext_vector_type(4)));
typedef unsigned short u16;

__device__ inline float bf2f(u16 u) {
    union { unsigned int i; float f; } x; x.i = ((unsigned int)u) << 16; return x.f;
}
__device__ inline u16 f2bf(float f) {
    union { float f; unsigned int i; } x; x.f = f;
    unsigned int r = x.i + 0x7fffu + ((x.i >> 16) & 1u);
    return (u16)(r >> 16);
}

// async global->LDS, 16B per lane; LDS dest is wave-uniform base + lane*16
__device__ __forceinline__ void ldsload16(const u16* g, u16* l) {
    __builtin_amdgcn_global_load_lds(
        (const __attribute__((address_space(1))) unsigned int*)g,
        (__attribute__((address_space(3))) unsigned int*)l, 16, 0, 0);
}

// ---------------- all weights f32 -> bf16, one launch ----------------
__global__ __launch_bounds__(256)
void cvt_all(const float4* __restrict__ wq, const float4* __restrict__ wk,
             const float4* __restrict__ wv, const float4* __restrict__ wo,
             const float4* __restrict__ w1, const float4* __restrict__ w2,
             const float4* __restrict__ w3,
             ushort4* wqb, ushort4* wkb, ushort4* wvb, ushort4* wob,
             ushort4* w1b, ushort4* w2b, ushort4* w3b) {
    const int WS4 = (D_MODEL * D_MODEL) / 4;   // 147456
    const int WB4 = (F_DIM * D_MODEL) / 4;     // 589824
    int i = blockIdx.x * 256 + threadIdx.x;
    const float4* src; ushort4* dst; int off;
    if (i < 4 * WS4) {
        int s = i / WS4; off = i - s * WS4;
        src = (s == 0) ? wq : (s == 1) ? wk : (s == 2) ? wv : wo;
        dst = (s == 0) ? wqb : (s == 1) ? wkb : (s == 2) ? wvb : wob;
    } else {
        int j = i - 4 * WS4; int s = j / WB4; off = j - s * WB4;
        src = (s == 0) ? w1 : (s == 1) ? w2 : w3;
        dst = (s == 0) ? w1b : (s == 1) ? w2b : w3b;
    }
    float4 v = src[off];
    ushort4 o;
    o.x = f2bf(v.x); o.y = f2bf(v.y); o.z = f2bf(v.z); o.w = f2bf(v.w);
    dst[off] = o;
}

// ---------------- RMSNorm: f32 in, bf16 out, one block per row --------------
__global__ __launch_bounds__(256)
void rmsnorm_k(const float* __restrict__ x, const float* __restrict__ g, u16* __restrict__ out) {
    int row = blockIdx.x;
    const float* xr = x + (size_t)row * D_MODEL;
    u16* orow = out + (size_t)row * D_MODEL;
    int t = threadIdx.x;
    float v0 = xr[t];
    float v1 = xr[t + 256];
    float v2 = xr[t + 512];
    float ss = v0 * v0 + v1 * v1 + v2 * v2;
    #pragma unroll
    for (int off = 1; off < 64; off <<= 1) ss += __shfl_xor(ss, off);
    __shared__ float red[4];
    if ((t & 63) == 0) red[t >> 6] = ss;
    __syncthreads();
    float tot = red[0] + red[1] + red[2] + red[3];
    float scale = rsqrtf(tot * (1.0f / (float)D_MODEL) + 1e-5f);
    orow[t]       = f2bf(g[t]       * v0 * scale);
    orow[t + 256] = f2bf(g[t + 256] * v1 * scale);
    orow[t + 512] = f2bf(g[t + 512] * v2 * scale);
}

// ---------------- tiled GEMM, double-buffered LDS staging -------------------
// block tile (32*TM) x 128, BK=32. acc[M,N] = A[M,K] @ W[N,K]^T.
// MODE 1: C(f32) = acc + R(f32)
// MODE 2: C(bf16) = silu(acc1) * acc3  (dual weights B1=w1, B2=w3; TM=4 only)
template <int TM, int MODE>
__global__ __launch_bounds__(256)
void gemm_t(const u16* __restrict__ A, const u16* __restrict__ B1,
            const u16* __restrict__ B2, const float* __restrict__ R,
            void* __restrict__ Cout, int N, int K) {
    __shared__ u16 As[2][32 * TM][32];
    __shared__ u16 Bs[2][128][32];
    __shared__ u16 Bs2[(MODE == 2) ? 2 : 1][(MODE == 2) ? 128 : 1][32];

    int t = threadIdx.x;
    int w = t >> 6, lane = t & 63;
    int mBase = blockIdx.y * (32 * TM), nBase = blockIdx.x * 128;
    int lrow = lane & 15, quad = lane >> 4;
    int wm = (w >> 1) * (16 * TM), wn = (w & 1) * 64;

    int srow = lane >> 2, scol = (lane & 3) * 8;
    const u16* Ag  = A  + (size_t)(mBase + w * (8 * TM) + srow) * K + scol;
    const u16* Bg  = B1 + (size_t)(nBase + w * 32 + srow) * K + scol;
    const u16* B2g = (MODE == 2) ? (B2 + (size_t)(nBase + w * 32 + srow) * K + scol) : nullptr;

    auto stage = [&](int k0, int b) {
        if (TM == 4) {
            ldsload16(Ag + k0, &As[b][w * 32][0]);
            ldsload16(Ag + (size_t)16 * K + k0, &As[b][w * 32 + 16][0]);
        } else {
            ldsload16(Ag + k0, &As[b][w * 16][0]);
        }
        ldsload16(Bg + k0, &Bs[b][w * 32][0]);
        ldsload16(Bg + (size_t)16 * K + k0, &Bs[b][w * 32 + 16][0]);
        if (MODE == 2) {
            ldsload16(B2g + k0, &Bs2[b][w * 32][0]);
            ldsload16(B2g + (size_t)16 * K + k0, &Bs2[b][w * 32 + 16][0]);
        }
    };

    floatx4 zero = {0.f, 0.f, 0.f, 0.f};
    floatx4 acc[TM][4], acc2[(MODE == 2) ? TM : 1][(MODE == 2) ? 4 : 1];
    #pragma unroll
    for (int r = 0; r < TM; ++r)
        #pragma unroll
        for (int c = 0; c < 4; ++c) acc[r][c] = zero;
    if (MODE == 2)
        #pragma unroll
        for (int r = 0; r < TM; ++r)
            #pragma unroll
            for (int c = 0; c < 4; ++c) acc2[r][c] = zero;

    stage(0, 0);
    int cur = 0;
    for (int k0 = 0; k0 < K; k0 += 32) {
        __syncthreads();                  // stage(k0) landed; prev reads done
        if (k0 + 32 < K) stage(k0 + 32, cur ^ 1);

        bf16x8 af[TM];
        #pragma unroll
        for (int r = 0; r < TM; ++r) af[r] = *(const bf16x8*)&As[cur][wm + r * 16 + lrow][quad * 8];
        #pragma unroll
        for (int c = 0; c < 4; ++c) {
            bf16x8 bfr = *(const bf16x8*)&Bs[cur][wn + c * 16 + lrow][quad * 8];
            #pragma unroll
            for (int r = 0; r < TM; ++r)
                acc[r][c] = __builtin_amdgcn_mfma_f32_16x16x32_bf16(af[r], bfr, acc[r][c], 0, 0, 0);
            if (MODE == 2) {
                bf16x8 b2f = *(const bf16x8*)&Bs2[cur][wn + c * 16 + lrow][quad * 8];
                #pragma unroll
                for (int r = 0; r < TM; ++r)
                    acc2[r][c] = __builtin_amdgcn_mfma_f32_16x16x32_bf16(af[r], b2f, acc2[r][c], 0, 0, 0);
            }
        }
        cur ^= 1;
    }

    #pragma unroll
    for (int r = 0; r < TM; ++r) {
        #pragma unroll
        for (int c = 0; c < 4; ++c) {
            #pragma unroll
            for (int j = 0; j < 4; ++j) {
                int grow = mBase + wm + r * 16 + quad * 4 + j;
                int gcol = nBase + wn + c * 16 + lrow;
                size_t idx = (size_t)grow * N + gcol;
                float val = acc[r][c][j];
                if (MODE == 1) {
                    ((float*)Cout)[idx] = val + R[idx];
                } else {
                    float a = val;
                    ((u16*)Cout)[idx] = f2bf((a / (1.0f + __expf(-a))) * acc2[r][c][j]);
                }
            }
        }
    }
}

// ---------------- fused QKV GEMM (N = 3*768), V stored transposed -----------
__global__ __launch_bounds__(256)
void gemm_qkv(const u16* __restrict__ A, const u16* __restrict__ wq,
              const u16* __restrict__ wk, const u16* __restrict__ wv,
              u16* __restrict__ qb, u16* __restrict__ kb, u16* __restrict__ vt) {
    const int K = D_MODEL;
    __shared__ u16 As[2][128][32];
    __shared__ u16 Bs[2][128][32];

    int t = threadIdx.x;
    int w = t >> 6, lane = t & 63;
    int nb = blockIdx.x;
    int which = nb / 6;
    int mBase = blockIdx.y * 128, nBase = (nb % 6) * 128;
    const u16* B1 = (which == 0) ? wq : (which == 1) ? wk : wv;
    int lrow = lane & 15, quad = lane >> 4;
    int wm = (w >> 1) * 64, wn = (w & 1) * 64;

    int srow = lane >> 2, scol = (lane & 3) * 8;
    const u16* Ag = A  + (size_t)(mBase + w * 32 + srow) * K + scol;
    const u16* Bg = B1 + (size_t)(nBase + w * 32 + srow) * K + scol;

    auto stage = [&](int k0, int b) {
        ldsload16(Ag + k0, &As[b][w * 32][0]);
        ldsload16(Ag + (size_t)16 * K + k0, &As[b][w * 32 + 16][0]);
        ldsload16(Bg + k0, &Bs[b][w * 32][0]);
        ldsload16(Bg + (size_t)16 * K + k0, &Bs[b][w * 32 + 16][0]);
    };

    floatx4 zero = {0.f, 0.f, 0.f, 0.f};
    floatx4 acc[4][4];
    #pragma unroll
    for (int r = 0; r < 4; ++r)
        #pragma unroll
        for (int c = 0; c < 4; ++c) acc[r][c] = zero;

    stage(0, 0);
    int cur = 0;
    for (int k0 = 0; k0 < K; k0 += 32) {
        __syncthreads();
        if (k0 + 32 < K) stage(k0 + 32, cur ^ 1);
        bf16x8 af[4];
        #pragma unroll
        for (int r = 0; r < 4; ++r) af[r] = *(const bf16x8*)&As[cur][wm + r * 16 + lrow][quad * 8];
        #pragma unroll
        for (int c = 0; c < 4; ++c) {
            bf16x8 bfr = *(const bf16x8*)&Bs[cur][wn + c * 16 + lrow][quad * 8];
            #pragma unroll
            for (int r = 0; r < 4; ++r)
                acc[r][c] = __builtin_amdgcn_mfma_f32_16x16x32_bf16(af[r], bfr, acc[r][c], 0, 0, 0);
        }
        cur ^= 1;
    }

    u16* dst = (which == 0) ? qb : kb;
    #pragma unroll
    for (int r = 0; r < 4; ++r) {
        #pragma unroll
        for (int c = 0; c < 4; ++c) {
            #pragma unroll
            for (int j = 0; j < 4; ++j) {
                int grow = mBase + wm + r * 16 + quad * 4 + j;
                int gcol = nBase + wn + c * 16 + lrow;
                float val = acc[r][c][j];
                if (which == 2) {
                    int bb = grow >> 11, s = grow & 2047;
                    int hh = gcol >> 6, d = gcol & 63;
                    vt[((((size_t)bb * NH + hh) * DK + d) << 11) + s] = f2bf(val);
                } else {
                    dst[(size_t)grow * D_MODEL + gcol] = f2bf(val);
                }
            }
        }
    }
}

// ---------------- MFMA flash attention -------------------------------------
// Block: 64 q-rows of one (b,h); 4 waves, wave w owns q-rows w*16..w*16+15.
// P = exp(S/8)*mask unnormalized (scores O(1), no max subtraction needed),
// row-sum deferred to epilogue. V pre-transposed [d][s].
__global__ __launch_bounds__(256)
void attn_mfma(const u16* __restrict__ q, const u16* __restrict__ k,
               const u16* __restrict__ vt, const int* __restrict__ mask,
               u16* __restrict__ out) {
    __shared__ u16 Qs0[64][32], Qs1[64][32];
    __shared__ u16 Ks0[64][32], Ks1[64][32];
    __shared__ u16 Vs0[64][32], Vs1[64][32];
    __shared__ u16 Ms[64][72];
    __shared__ u16 Ps[4][16][72];

    int t = threadIdx.x;
    int lane = t & 63;
    int w = t >> 6;
    int lrow = lane & 15;
    int quad = lane >> 4;

    int st0 = blockIdx.x * 64;
    int bh = blockIdx.y;
    int h = bh % NH;
    int b = bh / NH;

    const u16* qbase = q + ((size_t)b * S_LEN + st0) * D_MODEL + h * DK;
    const u16* kbase = k + (size_t)b * S_LEN * D_MODEL + h * DK;
    const u16* vbase = vt + (size_t)bh * DK * S_LEN;
    const int* mbase = mask + ((size_t)b * S_LEN + st0) * S_LEN;

    int srow = lane >> 2;          // staging row within 16-row chunk
    int scol = (lane & 3) * 8;     // staging col (elems)

    // ---- stage Q tile (64x64) once ----
    const u16* qg = qbase + (size_t)(w * 16 + srow) * D_MODEL + scol;
    ldsload16(qg, &Qs0[w * 16][0]);
    ldsload16(qg + 32, &Qs1[w * 16][0]);
    __syncthreads();
    bf16x8 aq0 = *(const bf16x8*)&Qs0[w * 16 + lrow][quad * 8];
    bf16x8 aq1 = *(const bf16x8*)&Qs1[w * 16 + lrow][quad * 8];

    const u16* kg = kbase + (size_t)(w * 16 + srow) * D_MODEL + scol;
    const u16* vg = vbase + (size_t)(w * 16 + srow) * S_LEN + scol;

    floatx4 zero = {0.f, 0.f, 0.f, 0.f};
    floatx4 Ot[4] = {zero, zero, zero, zero};
    float lsum[4] = {0.f, 0.f, 0.f, 0.f};

    for (int kt = 0; kt < S_LEN; kt += 64) {
        __syncthreads();   // previous tile's LDS reads done
        ldsload16(kg + (size_t)kt * D_MODEL, &Ks0[w * 16][0]);
        ldsload16(kg + (size_t)kt * D_MODEL + 32, &Ks1[w * 16][0]);
        ldsload16(vg + kt, &Vs0[w * 16][0]);
        ldsload16(vg + kt + 32, &Vs1[w * 16][0]);
        // mask tile 64x64 ints -> bf16 0/1 in LDS (coalesced int4 loads)
        #pragma unroll
        for (int it = 0; it < 4; ++it) {
            int i = t + it * 256;
            int row = i >> 4, c4 = (i & 15) * 4;
            int4 mv = *(const int4*)(mbase + (size_t)row * S_LEN + kt + c4);
            ushort4 o;
            o.x = mv.x ? 0x3F80 : 0; o.y = mv.y ? 0x3F80 : 0;
            o.z = mv.z ? 0x3F80 : 0; o.w = mv.w ? 0x3F80 : 0;
            *(ushort4*)&Ms[row][c4] = o;
        }
        __syncthreads();

        // --- S = Q K^T  (16 q-rows x 64 keys per wave) ---
        floatx4 st[4];
        #pragma unroll
        for (int nt = 0; nt < 4; ++nt) {
            bf16x8 bk0 = *(const bf16x8*)&Ks0[nt * 16 + lrow][quad * 8];
            bf16x8 bk1 = *(const bf16x8*)&Ks1[nt * 16 + lrow][quad * 8];
            st[nt] = __builtin_amdgcn_mfma_f32_16x16x32_bf16(aq0, bk0, zero, 0, 0, 0);
            st[nt] = __builtin_amdgcn_mfma_f32_16x16x32_bf16(aq1, bk1, st[nt], 0, 0, 0);
        }

        // --- P = mask * exp(S/8); stash to LDS in A-layout; row-sums ---
        #pragma unroll
        for (int j = 0; j < 4; ++j) {
            int qrow = w * 16 + quad * 4 + j;
            #pragma unroll
            for (int nt = 0; nt < 4; ++nt) {
                float m = bf2f(Ms[qrow][nt * 16 + lrow]);
                float e = m * __expf(st[nt][j] * 0.125f);
                lsum[j] += e;
                Ps[w][quad * 4 + j][nt * 16 + lrow] = f2bf(e);
            }
        }

        // --- O += P V ---
        bf16x8 ap0 = *(const bf16x8*)&Ps[w][lrow][quad * 8];
        bf16x8 ap1 = *(const bf16x8*)&Ps[w][lrow][32 + quad * 8];
        #pragma unroll
        for (int dt = 0; dt < 4; ++dt) {
            bf16x8 bv0 = *(const bf16x8*)&Vs0[dt * 16 + lrow][quad * 8];
            bf16x8 bv1 = *(const bf16x8*)&Vs1[dt * 16 + lrow][quad * 8];
            Ot[dt] = __builtin_amdgcn_mfma_f32_16x16x32_bf16(ap0, bv0, Ot[dt], 0, 0, 0);
            Ot[dt] = __builtin_amdgcn_mfma_f32_16x16x32_bf16(ap1, bv1, Ot[dt], 0, 0, 0);
        }
    }

    // --- row sums across the 16 lanes of each quad, then write O / l ---
    #pragma unroll
    for (int j = 0; j < 4; ++j) {
        #pragma unroll
        for (int off = 1; off < 16; off <<= 1) lsum[j] += __shfl_xor(lsum[j], off);
        lsum[j] = 1.0f / lsum[j];
    }
    u16* obase = out + ((size_t)b * S_LEN + st0 + w * 16) * D_MODEL + h * DK;
    #pragma unroll
    for (int dt = 0; dt < 4; ++dt)
        #pragma unroll
        for (int j = 0; j < 4; ++j)
            obase[(size_t)(quad * 4 + j) * D_MODEL + dt * 16 + lrow] = f2bf(Ot[dt][j] * lsum[j]);
}

// ---------------- host launch ----------------
extern "C" void kernel_launch(void* const* d_in, const int* in_sizes, int n_in,
                              void* d_out, int out_size, void* d_ws, size_t ws_size,
                              hipStream_t stream) {
    const float* x      = (const float*)d_in[0];
    const int*   mask   = (const int*)d_in[1];
    const float* wq     = (const float*)d_in[2];
    const float* wk     = (const float*)d_in[3];
    const float* wv     = (const float*)d_in[4];
    const float* wo     = (const float*)d_in[5];
    const float* w1     = (const float*)d_in[6];
    const float* w2     = (const float*)d_in[7];
    const float* w3     = (const float*)d_in[8];
    const float* g_attn = (const float*)d_in[9];
    const float* g_ffn  = (const float*)d_in[10];
    float* out = (float*)d_out;

    const size_t WSMALL = (size_t)D_MODEL * D_MODEL;
    const size_t WBIG   = (size_t)F_DIM * D_MODEL;
    const size_t MD     = (size_t)M_ROWS * D_MODEL;

    char* ws = (char*)d_ws;
    u16* wqb = (u16*)ws;             ws += WSMALL * 2;
    u16* wkb = (u16*)ws;             ws += WSMALL * 2;
    u16* wvb = (u16*)ws;             ws += WSMALL * 2;
    u16* wob = (u16*)ws;             ws += WSMALL * 2;
    u16* w1b = (u16*)ws;             ws += WBIG * 2;
    u16* w2b = (u16*)ws;             ws += WBIG * 2;
    u16* w3b = (u16*)ws;             ws += WBIG * 2;
    u16* xn  = (u16*)ws;             ws += MD * 2;       // also hn (reuse)
    u16* qb  = (u16*)ws;             ws += MD * 2;       // qb..ao contiguous = ub [M,F]
    u16* kb  = (u16*)ws;             ws += MD * 2;
    u16* vb  = (u16*)ws;             ws += MD * 2;       // V^T [B][NH][DK][S]
    u16* ao  = (u16*)ws;             ws += MD * 2;
    float* hb = (float*)ws;          ws += MD * 4;
    u16* hn = xn;
    u16* ub = qb;   // [M, F] bf16, reuses qb..ao (4*MD == M*F)
    (void)ws_size; (void)n_in; (void)in_sizes; (void)out_size;

    dim3 blk(256);

    cvt_all<<<9216, blk, 0, stream>>>((const float4*)wq, (const float4*)wk, (const float4*)wv,
                                      (const float4*)wo, (const float4*)w1, (const float4*)w2,
                                      (const float4*)w3,
                                      (ushort4*)wqb, (ushort4*)wkb, (ushort4*)wvb, (ushort4*)wob,
                                      (ushort4*)w1b, (ushort4*)w2b, (ushort4*)w3b);

    rmsnorm_k<<<M_ROWS, blk, 0, stream>>>(x, g_attn, xn);
    gemm_qkv<<<dim3(18, M_ROWS / 128), blk, 0, stream>>>(xn, wqb, wkb, wvb, qb, kb, vb);
    attn_mfma<<<dim3(S_LEN / 64, BATCH * NH), blk, 0, stream>>>(qb, kb, vb, mask, ao);
    gemm_t<2, 1><<<dim3(D_MODEL / 128, M_ROWS / 64), blk, 0, stream>>>(ao, wob, nullptr, x, hb, D_MODEL, D_MODEL);
    rmsnorm_k<<<M_ROWS, blk, 0, stream>>>((const float*)hb, g_ffn, hn);
    gemm_t<4, 2><<<dim3(F_DIM / 128, M_ROWS / 128), blk, 0, stream>>>(hn, w1b, w3b, nullptr, ub, F_DIM, D_MODEL);
    gemm_t<2, 1><<<dim3(D_MODEL / 128, M_ROWS / 64), blk, 0, stream>>>(ub, w2b, nullptr, hb, out, D_MODEL, F_DIM);
}